// Round 16
// baseline (782.883 us; speedup 1.0000x reference)
//
#include <hip/hip_runtime.h>
#include <hip/hip_bf16.h>
#include <math.h>

typedef __bf16 bf16_t;
typedef __bf16 bf16x4 __attribute__((ext_vector_type(4)));
typedef __bf16 bf16x8 __attribute__((ext_vector_type(8)));
typedef float  f32x4  __attribute__((ext_vector_type(4)));

#define DIN   3072
#define NOUT  24576
#define HALF  12288
#define MTOK  4096
#define BM    128
#define BN    96
#define BK    64
#define NT    48          // DIN / BK

// fused-prepass block ranges (small kernels first: overlap under quant_w's body)
#define NB_LORA  (MTOK / 8)                       // 512
#define NB_QX    (MTOK)                           // 4096
#define NB_CVT   (NOUT * 32 / 4 / 256)            // 768
#define NB_QW    (NOUT * (DIN / 4) / 256)         // 73728
#define B0       (NB_LORA)
#define B1       (B0 + NB_QX)
#define B2       (B1 + NB_CVT)
#define NB_PREP  (B2 + NB_QW)

#define GLD16(gp, lp) \
    __builtin_amdgcn_global_load_lds((const __attribute__((address_space(1))) void*)(gp), \
                                     (__attribute__((address_space(3))) void*)(lp), 16, 0, 0)

#define BAR()    __builtin_amdgcn_s_barrier()
#define WAITV(N) asm volatile("s_waitcnt vmcnt(" #N ")" ::: "memory")
#define SCHED0() __builtin_amdgcn_sched_barrier(0)

// ---------------- fused prepass: lora_t | quant_x | cvt_lu | quant_w --------------
__global__ __launch_bounds__(256) void k_prep(const float* __restrict__ x,
                                              const float* __restrict__ w,
                                              const float* __restrict__ ld,
                                              const float* __restrict__ lu,
                                              bf16_t* __restrict__ xq,
                                              bf16_t* __restrict__ wq,
                                              bf16_t* __restrict__ T,
                                              bf16_t* __restrict__ lub) {
    const int bid = blockIdx.x;
    const int t = threadIdx.x;

    if (bid < B0) {
        // ---- T = x @ lora_down^T (full-precision x), 8 tokens x 32 ranks ----
        int r = t & 31;
        int m = bid * 8 + (t >> 5);
        const float4* xr = reinterpret_cast<const float4*>(x + (size_t)m * DIN);
        const float4* lr = reinterpret_cast<const float4*>(ld + (size_t)r * DIN);
        float acc = 0.f;
#pragma unroll 4
        for (int i = 0; i < DIN / 4; ++i) {
            float4 a = xr[i], b = lr[i];
            acc += a.x * b.x + a.y * b.y + a.z * b.z + a.w * b.w;
        }
        T[(size_t)m * 32 + r] = (bf16_t)acc;
    } else if (bid < B1) {
        // ---- per-token activation int4 fake-quant -> bf16 ----
        int m = bid - B0;
        const float4* row = reinterpret_cast<const float4*>(x + (size_t)m * DIN);
        float4 v[3];
        float vm = 0.f;
#pragma unroll
        for (int i = 0; i < 3; ++i) {
            v[i] = row[t + i * 256];
            vm = fmaxf(vm, fmaxf(fmaxf(fabsf(v[i].x), fabsf(v[i].y)),
                                 fmaxf(fabsf(v[i].z), fabsf(v[i].w))));
        }
#pragma unroll
        for (int d = 1; d < 64; d <<= 1) vm = fmaxf(vm, __shfl_xor(vm, d));
        __shared__ float sm[4];
        if ((t & 63) == 0) sm[t >> 6] = vm;
        __syncthreads();
        vm = fmaxf(fmaxf(sm[0], sm[1]), fmaxf(sm[2], sm[3]));
        float s = fmaxf(vm * (1.f / 7.f), 1e-8f);
        float inv = 1.f / s;
        bf16x4* orow = reinterpret_cast<bf16x4*>(xq + (size_t)m * DIN);
#pragma unroll
        for (int i = 0; i < 3; ++i) {
            bf16x4 o;
            o[0] = (bf16_t)(fminf(fmaxf(rintf(v[i].x * inv), -8.f), 7.f) * s);
            o[1] = (bf16_t)(fminf(fmaxf(rintf(v[i].y * inv), -8.f), 7.f) * s);
            o[2] = (bf16_t)(fminf(fmaxf(rintf(v[i].z * inv), -8.f), 7.f) * s);
            o[3] = (bf16_t)(fminf(fmaxf(rintf(v[i].w * inv), -8.f), 7.f) * s);
            orow[t + i * 256] = o;
        }
    } else if (bid < B2) {
        // ---- cast lora_up f32 -> bf16 ----
        size_t idx = (size_t)(bid - B1) * 256 + t;
        float4 v = reinterpret_cast<const float4*>(lu)[idx];
        bf16x4 o;
        o[0] = (bf16_t)v.x; o[1] = (bf16_t)v.y; o[2] = (bf16_t)v.z; o[3] = (bf16_t)v.w;
        reinterpret_cast<bf16x4*>(lub)[idx] = o;
    } else {
        // ---- per-(row, group-of-64) weight int4 fake-quant -> bf16 ----
        size_t idx = (size_t)(bid - B2) * 256 + t;   // f32x4 index
        f32x4 v = __builtin_nontemporal_load(reinterpret_cast<const f32x4*>(w) + idx);
        float vm = fmaxf(fmaxf(fabsf(v[0]), fabsf(v[1])), fmaxf(fabsf(v[2]), fabsf(v[3])));
        vm = fmaxf(vm, __shfl_xor(vm, 1));
        vm = fmaxf(vm, __shfl_xor(vm, 2));
        vm = fmaxf(vm, __shfl_xor(vm, 4));
        vm = fmaxf(vm, __shfl_xor(vm, 8));
        float s = fmaxf(vm * (1.f / 7.f), 1e-8f);
        float inv = 1.f / s;
        bf16x4 o;
        o[0] = (bf16_t)(fminf(fmaxf(rintf(v[0] * inv), -8.f), 7.f) * s);
        o[1] = (bf16_t)(fminf(fmaxf(rintf(v[1] * inv), -8.f), 7.f) * s);
        o[2] = (bf16_t)(fminf(fmaxf(rintf(v[2] * inv), -8.f), 7.f) * s);
        o[3] = (bf16_t)(fminf(fmaxf(rintf(v[3] * inv), -8.f), 7.f) * s);
        reinterpret_cast<bf16x4*>(wq)[idx] = o;
    }
}

// ---------------- K4: BN=96 fully double-buffered fused GEMM, 2 blocks/CU ---------
// 512 thr = 8 waves. Waves 0-3: H (2x2 over 128x96, 48 cols/wave); 4-7: G.
// LDS: A dbuf 2x16K + B dbuf 2x24K (BH rows 0-95 | BG rows 96-191) = 80 KB
// -> exactly 2 blocks/CU. Per tile: stage(t+1 -> buf^1) at TOP (5 gld_lds),
// ds_read + 24 MFMA, WAITV(0) covered by the whole tile's compute, ONE barrier.
// Same barrier count & DMA volume as r9/r15; drains exposed -> covered.
__global__ __launch_bounds__(512, 4) void k_gemm(const bf16_t* __restrict__ xq,
                                                 const bf16_t* __restrict__ wq,
                                                 const bf16_t* __restrict__ T,
                                                 const bf16_t* __restrict__ lub,
                                                 float* __restrict__ out) {
    __shared__ __align__(16) char smem[81920];   // A dbuf 32K | B dbuf 48K; exch 51.2K

    int tid = threadIdx.x, lane = tid & 63, w = tid >> 6;
    int half = w >> 2;                 // 0 = H, 1 = G
    int wr = (w & 3) >> 1, wc = w & 1;
    const int l15 = lane & 15, lhi = lane >> 4;

    // XCD-bijective swizzle (grid 4096 % 8 == 0)
    int nwg = gridDim.x;
    int cpx = nwg >> 3;
    int swz = (blockIdx.x & 7) * cpx + (blockIdx.x >> 3);
    int mt = swz & 31, nt = swz >> 5;  // mt fast: neighbors share B panels
    int m0 = mt * BM, c0 = nt * BN;

    f32x4 acc[4][3];
#pragma unroll
    for (int i = 0; i < 4; ++i)
#pragma unroll
        for (int j = 0; j < 3; ++j) acc[i][j] = (f32x4){0.f, 0.f, 0.f, 0.f};

    // hoisted staging pointers. A: 1024 chunks (2/thread); B super-tile 192 rows
    // (BH 0-95, BG 96-191), 1536 chunks (3/thread). XOR key row&7 (96%8==0 keeps
    // BG continuous). LDS dest linear = chunk*16.
    const bf16_t* pS[5];
    {
        int ca0 = tid, ca1 = tid + 512;
        int ra0 = ca0 >> 3, ra1 = ca1 >> 3;
        pS[0] = xq + (size_t)(m0 + ra0) * DIN + ((ca0 & 7) ^ (ra0 & 7)) * 8;
        pS[1] = xq + (size_t)(m0 + ra1) * DIN + ((ca1 & 7) ^ (ra1 & 7)) * 8;
#pragma unroll
        for (int j = 0; j < 3; ++j) {
            int c = tid + j * 512;
            int rs = c >> 3;                       // super-row 0..191
            int grow = (rs < 96) ? (c0 + rs) : (c0 + HALF + rs - 96);
            pS[2 + j] = wq + (size_t)grow * DIN + ((c & 7) ^ (rs & 7)) * 8;
        }
    }

    // ds_read byte offsets (A region 16K; B region 24K as 192 rows x 128B)
    int offA[4][2], offB[3][2];
#pragma unroll
    for (int ks = 0; ks < 2; ++ks) {
        int c16 = ks * 4 + lhi;
#pragma unroll
        for (int i = 0; i < 4; ++i) {
            int ra = wr * 64 + i * 16 + l15;
            offA[i][ks] = ra * 128 + ((c16 ^ (ra & 7)) << 4);
        }
#pragma unroll
        for (int n = 0; n < 3; ++n) {
            int rb = half * 96 + wc * 48 + n * 16 + l15;   // super-row
            offB[n][ks] = rb * 128 + ((c16 ^ (rb & 7)) << 4);
        }
    }

#define STAGE96(bA, bB)                                                       \
    do {                                                                      \
        GLD16(pS[0], (bA) + tid * 16);                                        \
        GLD16(pS[1], (bA) + (tid + 512) * 16);                                \
        GLD16(pS[2], (bB) + tid * 16);                                        \
        GLD16(pS[3], (bB) + (tid + 512) * 16);                                \
        GLD16(pS[4], (bB) + (tid + 1024) * 16);                               \
    } while (0)

    // ---- prologue: stage tile 0 into buf0 ----
    STAGE96((char*)smem, (char*)smem + 32768);
#pragma unroll
    for (int p = 0; p < 5; ++p) pS[p] += BK;
    WAITV(0);
    BAR();
    SCHED0();

    for (int t = 0; t < NT; ++t) {
        const char* cA = (const char*)smem + (t & 1) * 16384;
        const char* cB = (const char*)smem + 32768 + (t & 1) * 24576;
        char* nA = (char*)smem + ((t + 1) & 1) * 16384;
        char* nB = (char*)smem + 32768 + ((t + 1) & 1) * 24576;

        STAGE96(nA, nB);      // tile t+1 (last iter: redundant re-stage of NT-1)

        bf16x8 a[4][2], b[3][2];
#pragma unroll
        for (int ks = 0; ks < 2; ++ks) {
#pragma unroll
            for (int i = 0; i < 4; ++i)
                a[i][ks] = *reinterpret_cast<const bf16x8*>(cA + offA[i][ks]);
#pragma unroll
            for (int n = 0; n < 3; ++n)
                b[n][ks] = *reinterpret_cast<const bf16x8*>(cB + offB[n][ks]);
        }
#pragma unroll
        for (int m = 0; m < 4; ++m)
#pragma unroll
            for (int n = 0; n < 3; ++n)
#pragma unroll
                for (int ks = 0; ks < 2; ++ks)
                    acc[m][n] = __builtin_amdgcn_mfma_f32_16x16x32_bf16(
                        a[m][ks], b[n][ks], acc[m][n], 0, 0, 0);

        WAITV(0);             // covered: t+1's DMA issued a full tile of compute ago
        BAR();                // WAR + cross-wave visibility, once per tile
        SCHED0();

        const int adv = (t + 2 < NT) ? BK : 0;
#pragma unroll
        for (int p = 0; p < 5; ++p) pS[p] += adv;
    }

    // ---- LoRA correction: one K=32 MFMA per fragment (RANK == 32) ----
    {
        bf16x8 tf[4];
#pragma unroll
        for (int m = 0; m < 4; ++m)
            tf[m] = *reinterpret_cast<const bf16x8*>(
                T + (size_t)(m0 + wr * 64 + m * 16 + l15) * 32 + lhi * 8);
#pragma unroll
        for (int n = 0; n < 3; ++n) {
            bf16x8 lu = *reinterpret_cast<const bf16x8*>(
                lub + (size_t)(c0 + half * HALF + wc * 48 + n * 16 + l15) * 32 + lhi * 8);
#pragma unroll
            for (int m = 0; m < 4; ++m)
                acc[m][n] = __builtin_amdgcn_mfma_f32_16x16x32_bf16(tf[m], lu, acc[m][n], 0, 0, 0);
        }
    }

    // ---- GEGLU epilogue: exch [128][100] f32 (pad: 100%32=4 -> conflict-free),
    //      G writes gl, H multiplies in place, all stream out as nt f32x4 ----
    __syncthreads();                    // staging drained by last loop WAITV+BAR
    float* exch = (float*)smem;
    if (half) {
#pragma unroll
        for (int m = 0; m < 4; ++m)
#pragma unroll
            for (int n = 0; n < 3; ++n) {
                int col = wc * 48 + n * 16 + l15;
#pragma unroll
                for (int r = 0; r < 4; ++r) {
                    int row = wr * 64 + m * 16 + lhi * 4 + r;
                    float g = acc[m][n][r];
                    float gl = 0.5f * g * (1.0f + erff(g * 0.70710678118654752f));
                    exch[row * 100 + col] = gl;
                }
            }
    }
    __syncthreads();
    if (!half) {
        // in-place: each slot read+written by exactly one lane
#pragma unroll
        for (int m = 0; m < 4; ++m)
#pragma unroll
            for (int n = 0; n < 3; ++n) {
                int col = wc * 48 + n * 16 + l15;
#pragma unroll
                for (int r = 0; r < 4; ++r) {
                    int row = wr * 64 + m * 16 + lhi * 4 + r;
                    int sidx = row * 100 + col;
                    exch[sidx] = acc[m][n][r] * exch[sidx];
                }
            }
    }
    __syncthreads();
    // stream 128x96 f32 out: 3072 f32x4 chunks, 6 per thread, coalesced nt stores
#pragma unroll
    for (int i = 0; i < 6; ++i) {
        int idx = i * 512 + tid;
        int row = idx / 24;             // 24 chunks per 96-col row
        int c4 = idx - row * 24;
        f32x4 v = *reinterpret_cast<const f32x4*>(exch + row * 100 + c4 * 4);
        __builtin_nontemporal_store(v, reinterpret_cast<f32x4*>(
            out + (size_t)(m0 + row) * HALF + c0 + c4 * 4));
    }
#undef STAGE96
}

extern "C" void kernel_launch(void* const* d_in, const int* in_sizes, int n_in,
                              void* d_out, int out_size, void* d_ws, size_t ws_size,
                              hipStream_t stream) {
    const float* x  = (const float*)d_in[0];   // [1,4096,3072]
    const float* wr = (const float*)d_in[1];   // [24576,3072]
    const float* ld = (const float*)d_in[2];   // [32,3072]
    const float* lu = (const float*)d_in[3];   // [24576,32]
    float* out = (float*)d_out;                // [4096,12288] f32

    bf16_t* xq  = (bf16_t*)d_ws;
    bf16_t* wq  = xq + (size_t)MTOK * DIN;
    bf16_t* T   = wq + (size_t)NOUT * DIN;
    bf16_t* lub = T  + (size_t)MTOK * 32;

    k_prep<<<NB_PREP, 256, 0, stream>>>(x, wr, ld, lu, xq, wq, T, lub);
    k_gemm<<<(MTOK / BM) * (HALF / BN), 512, 0, stream>>>(xq, wq, T, lub, out);
}